// Round 1
// baseline (47.769 us; speedup 1.0000x reference)
//
#include <hip/hip_runtime.h>
#include <math.h>

#define EPS 1e-12f

constexpr int Bn  = 64;    // batch
constexpr int Np  = 512;   // N == M == 512
constexpr int CH  = 64;    // loop-chunk per block
constexpr int MSPLIT = Np / CH;   // 8
constexpr int ROW = 2;     // owner points per thread
constexpr int TPB = 256;

__global__ void init_min_kernel(unsigned* __restrict__ w, int n) {
    int i = blockIdx.x * blockDim.x + threadIdx.x;
    if (i < n) w[i] = 0x7f800000u;   // +inf bits
}

// Pairwise min-dist^2 kernel. blockIdx.y==0: owner=p, loop=q (min over M);
// blockIdx.y==1: owner=q, loop=p (min over N). Stores min of
// (m_real^2 + (2*mi)^2) per owner point; sqrt(.+EPS) deferred to reduction.
__global__ __launch_bounds__(TPB) void chamfer_min_kernel(
        const float* __restrict__ p, const float* __restrict__ q,
        unsigned* __restrict__ wmin) {
    const int b     = blockIdx.x;
    const int pass  = blockIdx.y;
    const int chunk = blockIdx.z;
    const float* A  = (pass == 0) ? p : q;   // owner array (2,Bn,Np,4)
    const float* L  = (pass == 0) ? q : p;   // loop array
    unsigned* out   = wmin + (size_t)pass * Bn * Np + (size_t)b * Np;

    const int t = threadIdx.x;

    __shared__ float4 s_re[CH], s_im[CH];
    const float4* lre = (const float4*)(L + ((size_t)b * Np) * 4);
    const float4* lim = (const float4*)(L + ((size_t)(Bn + b) * Np) * 4);
    if (t < CH) {
        s_re[t] = lre[chunk * CH + t];
        s_im[t] = lim[chunk * CH + t];
    }

    const float4* are = (const float4*)(A + ((size_t)b * Np) * 4);
    const float4* aim = (const float4*)(A + ((size_t)(Bn + b) * Np) * 4);
    float4 pr[ROW], pi[ROW];
    int ia[ROW];
    #pragma unroll
    for (int r = 0; r < ROW; ++r) {
        ia[r] = t + r * TPB;
        pr[r] = are[ia[r]];
        pi[r] = aim[ia[r]];
    }
    __syncthreads();

    float smin[ROW];
    #pragma unroll
    for (int r = 0; r < ROW; ++r) smin[r] = 3.4e38f;

    #pragma unroll 4
    for (int k = 0; k < CH; ++k) {
        float4 qr = s_re[k];   // uniform address -> LDS broadcast, no conflicts
        float4 qi = s_im[k];
        #pragma unroll
        for (int r = 0; r < ROW; ++r) {
            float drx = pr[r].x - qr.x, dry = pr[r].y - qr.y;
            float drz = pr[r].z - qr.z, drw = pr[r].w - qr.w;
            float dix = pi[r].x - qi.x, diy = pi[r].y - qi.y;
            float diz = pi[r].z - qi.z, diw = pi[r].w - qi.w;
            float mr  = drx*drx - dry*dry - drz*drz - drw*drw;
            float mi  = drx*dix - dry*diy - drz*diz - drw*diw;
            float mi2 = mi + mi;
            float s   = mr*mr + mi2*mi2;
            smin[r]   = fminf(smin[r], s);
        }
    }

    #pragma unroll
    for (int r = 0; r < ROW; ++r)
        atomicMin(&out[ia[r]], __float_as_uint(smin[r]));  // >=0 floats: uint order == float order
}

__global__ __launch_bounds__(1024) void chamfer_reduce_kernel(
        const unsigned* __restrict__ wmin, float* __restrict__ outp) {
    __shared__ float red[1024];
    const int t = threadIdx.x;
    const int total = 2 * Bn * Np;   // 65536
    float acc = 0.f;
    for (int i = t; i < total; i += 1024)
        acc += sqrtf(__uint_as_float(wmin[i]) + EPS);
    red[t] = acc;
    __syncthreads();
    for (int s = 512; s > 0; s >>= 1) {
        if (t < s) red[t] += red[t + s];
        __syncthreads();
    }
    if (t == 0) outp[0] = red[0];
}

extern "C" void kernel_launch(void* const* d_in, const int* in_sizes, int n_in,
                              void* d_out, int out_size, void* d_ws, size_t ws_size,
                              hipStream_t stream) {
    const float* p = (const float*)d_in[0];   // (2, 64, 512, 4) fp32
    const float* q = (const float*)d_in[1];   // (2, 64, 512, 4) fp32
    float* out = (float*)d_out;
    unsigned* wmin = (unsigned*)d_ws;         // needs 2*64*512*4 = 256 KiB

    const int total = 2 * Bn * Np;
    init_min_kernel<<<total / 256, 256, 0, stream>>>(wmin, total);

    dim3 grid(Bn, 2, MSPLIT);                 // 64 x 2 x 8 = 1024 blocks
    chamfer_min_kernel<<<grid, TPB, 0, stream>>>(p, q, wmin);

    chamfer_reduce_kernel<<<1, 1024, 0, stream>>>(wmin, out);
}

// Round 2
// 36.147 us; speedup vs baseline: 1.3215x; 1.3215x over previous
//
#include <hip/hip_runtime.h>
#include <math.h>

#define EPS 1e-12f

constexpr int Bn = 64;            // batch
constexpr int Np = 512;           // N == M == 512
constexpr int OSPLIT = 2;         // owner splits per (b, pass)
constexpr int OWN = Np / OSPLIT;  // 256 owners per block
constexpr int TPB = 2 * OWN;      // 512 threads: low/high half take one k-half each
constexpr int KH = Np / 2;        // 256 loop points per thread

// One block = 256 owner points of one (batch, direction) slice; loops all 512
// opposite points from LDS. Threads t and t+256 share an owner, split the loop
// range, combine via LDS. Then sqrt + fixed-order block sum -> 1 partial/block.
__global__ __launch_bounds__(TPB) void chamfer_min_kernel(
        const float* __restrict__ p, const float* __restrict__ q,
        float* __restrict__ partial) {
    const int b    = blockIdx.x;
    const int pass = blockIdx.y;
    const int oc   = blockIdx.z;
    const float* A = (pass == 0) ? p : q;   // owner array   (2,Bn,Np,4)
    const float* L = (pass == 0) ? q : p;   // loop array

    __shared__ float4 s_re[Np], s_im[Np];   // 16 KiB
    const float4* lre = (const float4*)(L + (size_t)b * Np * 4);
    const float4* lim = (const float4*)(L + (size_t)(Bn + b) * Np * 4);
    const int t = threadIdx.x;
    for (int i = t; i < Np; i += TPB) { s_re[i] = lre[i]; s_im[i] = lim[i]; }

    const int o  = (t & (OWN - 1)) + oc * OWN;
    const int kh = t / OWN;                 // 0 or 1: which loop half
    const float4* are = (const float4*)(A + (size_t)b * Np * 4);
    const float4* aim = (const float4*)(A + (size_t)(Bn + b) * Np * 4);
    float4 pr = are[o], pi = aim[o];
    __syncthreads();

    float smin = 3.4e38f;
    const int k0 = kh * KH;
    #pragma unroll 8
    for (int k = k0; k < k0 + KH; ++k) {
        float4 qr = s_re[k];                // uniform index -> broadcast, no conflicts
        float4 qi = s_im[k];
        float drx = pr.x - qr.x, dry = pr.y - qr.y;
        float drz = pr.z - qr.z, drw = pr.w - qr.w;
        float dix = pi.x - qi.x, diy = pi.y - qi.y;
        float diz = pi.z - qi.z, diw = pi.w - qi.w;
        float mr  = drx*drx - dry*dry - drz*drz - drw*drw;
        float mi  = drx*dix - dry*diy - drz*diz - drw*diw;
        float mi2 = mi + mi;
        float s   = mr*mr + mi2*mi2;
        smin      = fminf(smin, s);
    }

    __shared__ float red[OWN];
    if (t >= OWN) red[t - OWN] = smin;
    __syncthreads();
    float v = 0.f;
    if (t < OWN) v = sqrtf(fminf(smin, red[t]) + EPS);
    __syncthreads();                        // safe to reuse red
    if (t < OWN) red[t] = v;
    __syncthreads();
    for (int s = OWN / 2; s > 0; s >>= 1) {
        if (t < s) red[t] += red[t + s];
        __syncthreads();
    }
    if (t == 0) partial[((size_t)pass * Bn + b) * OSPLIT + oc] = red[0];
}

// Deterministic fixed-order sum of the 256 block partials.
__global__ __launch_bounds__(256) void final_sum_kernel(
        const float* __restrict__ partial, float* __restrict__ outp) {
    __shared__ float red[256];
    const int t = threadIdx.x;
    red[t] = partial[t];
    __syncthreads();
    for (int s = 128; s > 0; s >>= 1) {
        if (t < s) red[t] += red[t + s];
        __syncthreads();
    }
    if (t == 0) outp[0] = red[0];
}

extern "C" void kernel_launch(void* const* d_in, const int* in_sizes, int n_in,
                              void* d_out, int out_size, void* d_ws, size_t ws_size,
                              hipStream_t stream) {
    const float* p = (const float*)d_in[0];   // (2, 64, 512, 4) fp32
    const float* q = (const float*)d_in[1];   // (2, 64, 512, 4) fp32
    float* out     = (float*)d_out;
    float* partial = (float*)d_ws;            // 2*Bn*OSPLIT = 256 floats

    dim3 grid(Bn, 2, OSPLIT);                 // 64 x 2 x 2 = 256 blocks, 1/CU
    chamfer_min_kernel<<<grid, TPB, 0, stream>>>(p, q, partial);
    final_sum_kernel<<<1, 256, 0, stream>>>(partial, out);
}

// Round 3
// 22.172 us; speedup vs baseline: 2.1544x; 1.6303x over previous
//
#include <hip/hip_runtime.h>
#include <math.h>

#define EPS 1e-12f

constexpr int Bn = 64;             // batch
constexpr int Np = 512;            // N == M == 512
constexpr int OSPLIT = 4;          // owner splits per (b, pass)
constexpr int OWN = Np / OSPLIT;   // 128 owners per block (64 pairs)
constexpr int TPB = 256;           // 4 waves: each wave takes one k-quarter
constexpr int KSPLIT = 4;
constexpr int KCH = Np / KSPLIT;   // 128 loop points per thread

// Each thread owns 2 adjacent owner points (registers) and scans a wave-uniform
// quarter of the 512 opposite points, read directly from global (wave-uniform
// address -> scalar/L1-broadcast load; data is L2-resident). No LDS in the hot
// loop. 4 k-quarter partial mins combined via tiny LDS, then sqrt + wave sum.
__global__ __launch_bounds__(TPB) void chamfer_min_kernel(
        const float* __restrict__ p, const float* __restrict__ q,
        float* __restrict__ partial) {
    const int b    = blockIdx.x;
    const int pass = blockIdx.y;
    const int oc   = blockIdx.z;
    const float* A = (pass == 0) ? p : q;   // owner array (2,Bn,Np,4)
    const float* L = (pass == 0) ? q : p;   // loop array

    const int t  = threadIdx.x;
    const int ot = t & 63;
    const int kh = __builtin_amdgcn_readfirstlane(t >> 6);  // wave-uniform quarter

    const float4* are = (const float4*)(A + (size_t)b * Np * 4);
    const float4* aim = (const float4*)(A + (size_t)(Bn + b) * Np * 4);
    const int o = oc * OWN + ot * 2;
    const float4 pr0 = are[o], pr1 = are[o + 1];
    const float4 pi0 = aim[o], pi1 = aim[o + 1];

    const float4* lre = (const float4*)(L + (size_t)b * Np * 4);
    const float4* lim = (const float4*)(L + (size_t)(Bn + b) * Np * 4);

    float s0 = 3.4e38f, s1 = 3.4e38f;
    const int k0 = kh * KCH;
    #pragma unroll 8
    for (int k = k0; k < k0 + KCH; ++k) {
        const float4 qr = lre[k];           // wave-uniform address
        const float4 qi = lim[k];
        {
            float drx = pr0.x - qr.x, dry = pr0.y - qr.y;
            float drz = pr0.z - qr.z, drw = pr0.w - qr.w;
            float dix = pi0.x - qi.x, diy = pi0.y - qi.y;
            float diz = pi0.z - qi.z, diw = pi0.w - qi.w;
            float mr  = drx*drx - dry*dry - drz*drz - drw*drw;
            float mi  = drx*dix - dry*diy - drz*diz - drw*diw;
            float mi2 = mi + mi;
            float s   = mr*mr + mi2*mi2;
            s0 = fminf(s0, s);
        }
        {
            float drx = pr1.x - qr.x, dry = pr1.y - qr.y;
            float drz = pr1.z - qr.z, drw = pr1.w - qr.w;
            float dix = pi1.x - qi.x, diy = pi1.y - qi.y;
            float diz = pi1.z - qi.z, diw = pi1.w - qi.w;
            float mr  = drx*drx - dry*dry - drz*drz - drw*drw;
            float mi  = drx*dix - dry*diy - drz*diz - drw*diw;
            float mi2 = mi + mi;
            float s   = mr*mr + mi2*mi2;
            s1 = fminf(s1, s);
        }
    }

    __shared__ float2 sred[TPB];
    sred[t] = make_float2(s0, s1);
    __syncthreads();
    if (t < 64) {
        float2 a  = sred[t];
        float2 b2 = sred[t + 64];
        float2 c  = sred[t + 128];
        float2 d  = sred[t + 192];
        float m0 = fminf(fminf(a.x, b2.x), fminf(c.x, d.x));
        float m1 = fminf(fminf(a.y, b2.y), fminf(c.y, d.y));
        float v = sqrtf(m0 + EPS) + sqrtf(m1 + EPS);
        #pragma unroll
        for (int off = 32; off > 0; off >>= 1)
            v += __shfl_down(v, off, 64);
        if (t == 0)
            partial[(((size_t)pass * Bn + b) * OSPLIT) + oc] = v;
    }
}

// Deterministic fixed-order sum of the 512 block partials.
__global__ __launch_bounds__(256) void final_sum_kernel(
        const float* __restrict__ partial, float* __restrict__ outp) {
    __shared__ float red[256];
    const int t = threadIdx.x;
    red[t] = partial[t] + partial[t + 256];
    __syncthreads();
    for (int s = 128; s > 0; s >>= 1) {
        if (t < s) red[t] += red[t + s];
        __syncthreads();
    }
    if (t == 0) outp[0] = red[0];
}

extern "C" void kernel_launch(void* const* d_in, const int* in_sizes, int n_in,
                              void* d_out, int out_size, void* d_ws, size_t ws_size,
                              hipStream_t stream) {
    const float* p = (const float*)d_in[0];   // (2, 64, 512, 4) fp32
    const float* q = (const float*)d_in[1];   // (2, 64, 512, 4) fp32
    float* out     = (float*)d_out;
    float* partial = (float*)d_ws;            // 2*Bn*OSPLIT = 512 floats

    dim3 grid(Bn, 2, OSPLIT);                 // 64 x 2 x 4 = 512 blocks, 2/CU
    chamfer_min_kernel<<<grid, TPB, 0, stream>>>(p, q, partial);
    final_sum_kernel<<<1, 256, 0, stream>>>(partial, out);
}